// Round 1
// baseline (1805.440 us; speedup 1.0000x reference)
//
#include <hip/hip_runtime.h>

#define N_ROWS 65536
#define KF 2048
#define KE 352
#define KPAD 2400
#define HID 1024
#define NCLS 37

// ---------- helpers ----------
__device__ __forceinline__ unsigned short f2bf(float x) {  // RNE
    unsigned u = __float_as_uint(x);
    return (unsigned short)((u + 0x7FFFu + ((u >> 16) & 1u)) >> 16);
}
__device__ __forceinline__ float bf2f(unsigned short h) {
    return __uint_as_float(((unsigned)h) << 16);
}
__device__ __forceinline__ unsigned pack_rne(float a, float b) {
    return (unsigned)f2bf(a) | ((unsigned)f2bf(b) << 16);
}
// truncation pack (1 v_perm_b32); batchnorm cancels the uniform scale bias
__device__ __forceinline__ unsigned pack_trunc(float a, float b) {
    return __byte_perm(__float_as_uint(a), __float_as_uint(b), 0x7632);
}

typedef __bf16 bf16x8 __attribute__((ext_vector_type(8)));
typedef float f32x4 __attribute__((ext_vector_type(4)));

__device__ __forceinline__ void gl2lds16(const void* g, void* l) {
    __builtin_amdgcn_global_load_lds((const __attribute__((address_space(1))) void*)g,
                                     (__attribute__((address_space(3))) void*)l, 16, 0, 0);
}

// ---------- K0: bn4 stats over center_size(boxes[:,1:5]) ----------
__global__ __launch_bounds__(256) void bn4_stats_k(const float* __restrict__ boxes,
                                                   float* __restrict__ stats4) {
    const int tid = threadIdx.x;
    const int r = blockIdx.x * 256 + tid;
    const float* b = boxes + (size_t)r * 5;
    float x1 = b[1], y1 = b[2], x2 = b[3], y2 = b[4];
    float w = x2 - x1, h = y2 - y1;
    float cx = x1 + 0.5f * w, cy = y1 + 0.5f * h;
    float v[8] = {cx, cy, w, h, cx * cx, cy * cy, w * w, h * h};
    #pragma unroll
    for (int c = 0; c < 8; c++) {
        #pragma unroll
        for (int o = 32; o > 0; o >>= 1) v[c] += __shfl_down(v[c], o, 64);
    }
    __shared__ float sh[4][8];
    const int lane = tid & 63, wv = tid >> 6;
    if (lane == 0) {
        #pragma unroll
        for (int c = 0; c < 8; c++) sh[wv][c] = v[c];
    }
    __syncthreads();
    if (tid < 8) atomicAdd(&stats4[tid], sh[0][tid] + sh[1][tid] + sh[2][tid] + sh[3][tid]);
}

// ---------- K1: build E = [obj_embed(200) | pos(128) | 0(24)] bf16 ----------
__global__ __launch_bounds__(256) void build_ae_k(
    const float* __restrict__ dist, const float* __restrict__ boxes,
    const float* __restrict__ objw, const float* __restrict__ bn4g,
    const float* __restrict__ bn4b, const float* __restrict__ posw,
    const float* __restrict__ posb, const float* __restrict__ stats4,
    unsigned short* __restrict__ Ae) {
    __shared__ __align__(16) float Wsh[7200];   // obj_embed_w [36,200]
    __shared__ __align__(16) float Psh[640];    // pos_w [4,128] + pos_b [128]
    __shared__ float Csh[64 * 4];
    __shared__ float sc4[4], sf4[4];
    const int t = threadIdx.x;
    const int r0 = blockIdx.x * 64;
    for (int i = t; i < 7200; i += 256) Wsh[i] = objw[i];
    for (int i = t; i < 512; i += 256) Psh[i] = posw[i];
    if (t < 128) Psh[512 + t] = posb[t];
    if (t < 4) {
        float m = stats4[t] * (1.0f / 65536.0f);
        float var = stats4[4 + t] * (1.0f / 65536.0f) - m * m;
        float sc = bn4g[t] * rsqrtf(var + 1e-5f);
        sc4[t] = sc; sf4[t] = bn4b[t] - m * sc;
    }
    __syncthreads();
    if (t < 64) {
        const float* b = boxes + (size_t)(r0 + t) * 5;
        float x1 = b[1], y1 = b[2], x2 = b[3], y2 = b[4];
        float w = x2 - x1, h = y2 - y1;
        float cx = x1 + 0.5f * w, cy = y1 + 0.5f * h;
        Csh[t * 4 + 0] = cx * sc4[0] + sf4[0];
        Csh[t * 4 + 1] = cy * sc4[1] + sf4[1];
        Csh[t * 4 + 2] = w * sc4[2] + sf4[2];
        Csh[t * 4 + 3] = h * sc4[3] + sf4[3];
    }
    __syncthreads();
    const int r = t >> 2, q = t & 3;
    float d[36];
    #pragma unroll
    for (int ii = 0; ii < 9; ii++)
        *(float4*)&d[ii * 4] = *(const float4*)(dist + (size_t)(r0 + r) * 36 + ii * 4);
    unsigned short* arow = Ae + (size_t)(r0 + r) * KE;
    for (int gg = q; gg < 50; gg += 4) {
        int c = gg * 4;
        float4 s = {0.f, 0.f, 0.f, 0.f};
        #pragma unroll
        for (int i = 0; i < 36; i++) {
            float4 wv = *(const float4*)&Wsh[i * 200 + c];
            s.x = fmaf(d[i], wv.x, s.x); s.y = fmaf(d[i], wv.y, s.y);
            s.z = fmaf(d[i], wv.z, s.z); s.w = fmaf(d[i], wv.w, s.w);
        }
        uint2 p; p.x = pack_rne(s.x, s.y); p.y = pack_rne(s.z, s.w);
        *(uint2*)(arow + c) = p;
    }
    const float c0v = Csh[r * 4 + 0], c1v = Csh[r * 4 + 1];
    const float c2v = Csh[r * 4 + 2], c3v = Csh[r * 4 + 3];
    for (int gg = q; gg < 32; gg += 4) {
        int c = gg * 4;
        float4 s = *(const float4*)&Psh[512 + c];
        float4 w0 = *(const float4*)&Psh[0 * 128 + c];
        float4 w1 = *(const float4*)&Psh[1 * 128 + c];
        float4 w2v = *(const float4*)&Psh[2 * 128 + c];
        float4 w3 = *(const float4*)&Psh[3 * 128 + c];
        s.x = fmaf(c0v, w0.x, fmaf(c1v, w1.x, fmaf(c2v, w2v.x, fmaf(c3v, w3.x, s.x))));
        s.y = fmaf(c0v, w0.y, fmaf(c1v, w1.y, fmaf(c2v, w2v.y, fmaf(c3v, w3.y, s.y))));
        s.z = fmaf(c0v, w0.z, fmaf(c1v, w1.z, fmaf(c2v, w2v.z, fmaf(c3v, w3.z, s.z))));
        s.w = fmaf(c0v, w0.w, fmaf(c1v, w1.w, fmaf(c2v, w2v.w, fmaf(c3v, w3.w, s.w))));
        s.x = fmaxf(s.x, 0.f); s.y = fmaxf(s.y, 0.f);
        s.z = fmaxf(s.z, 0.f); s.w = fmaxf(s.w, 0.f);
        uint2 p; p.x = pack_rne(s.x, s.y); p.y = pack_rne(s.z, s.w);
        *(uint2*)(arow + 200 + c) = p;
    }
    for (int f = t; f < 384; f += 256) {
        int rr = f / 6, gg = f % 6;
        uint2 z; z.x = 0u; z.y = 0u;
        *(uint2*)(Ae + (size_t)(r0 + rr) * KE + 328 + gg * 4) = z;
    }
}

// ---------- K2: Bt[n][k] = dec_w1[k][n] (bf16, zero-padded K) ----------
__global__ __launch_bounds__(256) void transpose_w1_k(const float* __restrict__ w1,
                                                      unsigned short* __restrict__ Bt) {
    __shared__ float sh[32][33];
    const int bk = (blockIdx.x % 75) * 32;
    const int bn = (blockIdx.x / 75) * 32;
    const int tx = threadIdx.x & 31, ty = threadIdx.x >> 5;
    for (int yy = ty; yy < 32; yy += 8) {
        int k = bk + yy;
        sh[tx][yy] = (k < 2376) ? w1[(size_t)k * HID + bn + tx] : 0.0f;
    }
    __syncthreads();
    for (int row = ty; row < 32; row += 8)
        Bt[(size_t)(bn + row) * KPAD + bk + tx] = f2bf(sh[row][tx]);
}

// ---------- K3: main GEMM  H[65536,1024] = bf16([F|E]) @ bf16(W1) ----------
#define COMPUTE_STEP()                                                                   \
    do {                                                                                 \
        bf16x8 af[4], bfr[4];                                                            \
        _Pragma("unroll") for (int i = 0; i < 4; i++)                                    \
            af[i] = *(const bf16x8*)(a_sh + (mw + i * 16 + fm) * 32 + fq * 8);           \
        _Pragma("unroll") for (int j = 0; j < 4; j++)                                    \
            bfr[j] = *(const bf16x8*)(b_sh + (nw + j * 16 + fm) * 32 + fq * 8);          \
        _Pragma("unroll") for (int i = 0; i < 4; i++)                                    \
            _Pragma("unroll") for (int j = 0; j < 4; j++)                                \
                acc[i][j] = __builtin_amdgcn_mfma_f32_16x16x32_bf16(af[i], bfr[j],       \
                                                                    acc[i][j], 0, 0, 0); \
    } while (0)

__global__ __launch_bounds__(256) void gemm1_k(
    const float* __restrict__ F, const unsigned short* __restrict__ Ae,
    const unsigned short* __restrict__ Bt, unsigned short* __restrict__ H) {
    __shared__ __align__(16) unsigned short a_sh[128 * 32];
    __shared__ __align__(16) unsigned short b_sh[128 * 32];
    const int tid = threadIdx.x;
    const int lane = tid & 63;
    const int wv = tid >> 6;
    const int n0 = (blockIdx.x & 7) * 128;   // n fastest -> A-tile LLC reuse
    const int m0 = (blockIdx.x >> 3) * 128;
    const int mw = (wv & 1) * 64, nw = (wv >> 1) * 64;
    const int fm = lane & 15, fq = lane >> 4;

    f32x4 acc[4][4];
    const f32x4 zero = {0.f, 0.f, 0.f, 0.f};
    #pragma unroll
    for (int i = 0; i < 4; i++)
        #pragma unroll
        for (int j = 0; j < 4; j++) acc[i][j] = zero;

    const float* fbase = F + (size_t)(m0 + (tid >> 3)) * KF + (tid & 7) * 4;
    const unsigned short* btbase = Bt + (size_t)(n0 + (tid >> 2)) * KPAD + (tid & 3) * 8;
    const unsigned short* aebase = Ae + (size_t)(m0 + (tid >> 2)) * KE + (tid & 3) * 8;
    unsigned short* a_dst32 = a_sh + (tid >> 3) * 32 + (tid & 7) * 4;
    unsigned short* a_dst = a_sh + tid * 8;
    unsigned short* b_dst = b_sh + tid * 8;

    // register prefetch of first fp32 A tile
    float4 av0 = *(const float4*)(fbase + 0);
    float4 av1 = *(const float4*)(fbase + 32 * KF);
    float4 av2 = *(const float4*)(fbase + 64 * KF);
    float4 av3 = *(const float4*)(fbase + 96 * KF);

    for (int k0 = 0; k0 < KF; k0 += 32) {
        __syncthreads();                       // prev compute done
        uint2 p0; p0.x = pack_trunc(av0.x, av0.y); p0.y = pack_trunc(av0.z, av0.w);
        uint2 p1; p1.x = pack_trunc(av1.x, av1.y); p1.y = pack_trunc(av1.z, av1.w);
        uint2 p2; p2.x = pack_trunc(av2.x, av2.y); p2.y = pack_trunc(av2.z, av2.w);
        uint2 p3; p3.x = pack_trunc(av3.x, av3.y); p3.y = pack_trunc(av3.z, av3.w);
        *(uint2*)(a_dst32 + 0)    = p0;
        *(uint2*)(a_dst32 + 1024) = p1;
        *(uint2*)(a_dst32 + 2048) = p2;
        *(uint2*)(a_dst32 + 3072) = p3;
        gl2lds16(btbase + k0, b_dst);
        gl2lds16(btbase + k0 + 64 * KPAD, b_dst + 2048);
        __syncthreads();                       // staging visible
        if (k0 + 32 < KF) {                    // prefetch next tile; latency hides under MFMA
            av0 = *(const float4*)(fbase + k0 + 32);
            av1 = *(const float4*)(fbase + k0 + 32 + 32 * KF);
            av2 = *(const float4*)(fbase + k0 + 32 + 64 * KF);
            av3 = *(const float4*)(fbase + k0 + 32 + 96 * KF);
        }
        COMPUTE_STEP();
    }
    for (int k0 = KF; k0 < KPAD; k0 += 32) {   // obj_embed/pos columns (bf16, async)
        __syncthreads();
        gl2lds16(aebase + (k0 - KF), a_dst);
        gl2lds16(aebase + (k0 - KF) + 64 * KE, a_dst + 2048);
        gl2lds16(btbase + k0, b_dst);
        gl2lds16(btbase + k0 + 64 * KPAD, b_dst + 2048);
        __syncthreads();
        COMPUTE_STEP();
    }
    #pragma unroll
    for (int i = 0; i < 4; i++)
        #pragma unroll
        for (int j = 0; j < 4; j++)
            #pragma unroll
            for (int r = 0; r < 4; r++) {
                int row = m0 + mw + i * 16 + fq * 4 + r;
                int col = n0 + nw + j * 16 + fm;
                H[(size_t)row * HID + col] = f2bf(acc[i][j][r]);
            }
}

// ---------- K4: bn1 column stats over H ----------
__global__ __launch_bounds__(256) void bn1_stats_k(const unsigned short* __restrict__ H,
                                                   float* __restrict__ stats1) {
    const int t = threadIdx.x;
    const int cb = blockIdx.x & 3;     // 4 col-blocks of 256
    const int rc = blockIdx.x >> 2;    // 256 row-chunks of 256
    const int c0 = cb * 256 + (t & 31) * 8;
    const int r0 = rc * 256 + (t >> 5);
    float s[8] = {0, 0, 0, 0, 0, 0, 0, 0}, q[8] = {0, 0, 0, 0, 0, 0, 0, 0};
    for (int i = 0; i < 32; i++) {
        const unsigned short* p = H + (size_t)(r0 + i * 8) * HID + c0;
        uint4 raw = *(const uint4*)p;
        unsigned wds[4] = {raw.x, raw.y, raw.z, raw.w};
        #pragma unroll
        for (int j = 0; j < 4; j++) {
            float v0 = bf2f((unsigned short)(wds[j] & 0xFFFFu));
            float v1 = bf2f((unsigned short)(wds[j] >> 16));
            s[2 * j] += v0; q[2 * j] += v0 * v0;
            s[2 * j + 1] += v1; q[2 * j + 1] += v1 * v1;
        }
    }
    __shared__ float sh[2048];
    #pragma unroll
    for (int j = 0; j < 8; j++) sh[t * 8 + j] = s[j];
    __syncthreads();
    if (t < 32) {
        float tot[8] = {0, 0, 0, 0, 0, 0, 0, 0};
        for (int rl = 0; rl < 8; rl++)
            #pragma unroll
            for (int j = 0; j < 8; j++) tot[j] += sh[(rl * 32 + t) * 8 + j];
        #pragma unroll
        for (int j = 0; j < 8; j++) atomicAdd(&stats1[cb * 256 + t * 8 + j], tot[j]);
    }
    __syncthreads();
    #pragma unroll
    for (int j = 0; j < 8; j++) sh[t * 8 + j] = q[j];
    __syncthreads();
    if (t < 32) {
        float tot[8] = {0, 0, 0, 0, 0, 0, 0, 0};
        for (int rl = 0; rl < 8; rl++)
            #pragma unroll
            for (int j = 0; j < 8; j++) tot[j] += sh[(rl * 32 + t) * 8 + j];
        #pragma unroll
        for (int j = 0; j < 8; j++) atomicAdd(&stats1[HID + cb * 256 + t * 8 + j], tot[j]);
    }
}

// ---------- K5: out = relu(bn1(H)) @ w2 + b2  (split-K x2, fp32 VALU) ----------
__global__ __launch_bounds__(256) void final_k(
    const unsigned short* __restrict__ H, const float* __restrict__ stats1,
    const float* __restrict__ g1, const float* __restrict__ b1,
    const float* __restrict__ w2, const float* __restrict__ b2,
    float* __restrict__ out) {
    __shared__ float scs[HID], sfs[HID];
    __shared__ float hh[2][128 * 33];
    const int t = threadIdx.x;
    const int r0 = blockIdx.x * 128;
    const int rloc = t & 127, kh = t >> 7;
    for (int k = t; k < HID; k += 256) {
        float m = stats1[k] * (1.0f / 65536.0f);
        float var = stats1[HID + k] * (1.0f / 65536.0f) - m * m;
        float sc = g1[k] * rsqrtf(var + 1e-5f);
        scs[k] = sc; sfs[k] = b1[k] - m * sc;
    }
    float acc[NCLS];
    #pragma unroll
    for (int c = 0; c < NCLS; c++) acc[c] = (kh == 0) ? b2[c] : 0.0f;
    __syncthreads();
    for (int k0 = 0; k0 < 512; k0 += 32) {
        __syncthreads();   // protect hh from previous iteration's readers
        #pragma unroll
        for (int rr = 0; rr < 4; rr++) {
            int idx = rr * 2048 + t * 8;
            int hhalf = idx >> 12;
            int within = idx & 4095;
            int row = within >> 5, kk = within & 31;
            int kg = hhalf * 512 + k0 + kk;
            const unsigned short* p = H + (size_t)(r0 + row) * HID + kg;
            uint4 raw = *(const uint4*)p;
            unsigned wds[4] = {raw.x, raw.y, raw.z, raw.w};
            float* dsthh = &hh[hhalf][row * 33 + kk];
            #pragma unroll
            for (int j = 0; j < 4; j++) {
                float v0 = bf2f((unsigned short)(wds[j] & 0xFFFFu));
                float v1 = bf2f((unsigned short)(wds[j] >> 16));
                int ka = kg + 2 * j, kb = kg + 2 * j + 1;
                v0 = fmaxf(fmaf(v0, scs[ka], sfs[ka]), 0.0f);
                v1 = fmaxf(fmaf(v1, scs[kb], sfs[kb]), 0.0f);
                dsthh[2 * j] = v0; dsthh[2 * j + 1] = v1;
            }
        }
        __syncthreads();
        const float* hrow = &hh[kh][rloc * 33];
        #pragma unroll 4
        for (int kk = 0; kk < 32; kk++) {
            float hv = hrow[kk];
            const float* wr = w2 + (size_t)(kh * 512 + k0 + kk) * NCLS;  // uniform -> s_load
            #pragma unroll
            for (int c = 0; c < NCLS; c++) acc[c] = fmaf(hv, wr[c], acc[c]);
        }
    }
    __syncthreads();
    float* red = &hh[0][0];
    if (kh == 1) {
        #pragma unroll
        for (int c = 0; c < NCLS; c++) red[rloc * NCLS + c] = acc[c];
    }
    __syncthreads();
    if (kh == 0) {
        float* op = out + (size_t)(r0 + rloc) * NCLS;
        #pragma unroll
        for (int c = 0; c < NCLS; c++) op[c] = acc[c] + red[rloc * NCLS + c];
    }
}

// ---------- launch ----------
extern "C" void kernel_launch(void* const* d_in, const int* in_sizes, int n_in,
                              void* d_out, int out_size, void* d_ws, size_t ws_size,
                              hipStream_t stream) {
    (void)in_sizes; (void)n_in; (void)out_size;
    const float* dist  = (const float*)d_in[0];
    const float* boxes = (const float*)d_in[1];
    const float* feat  = (const float*)d_in[2];
    const float* objw  = (const float*)d_in[3];
    const float* bn4g  = (const float*)d_in[4];
    const float* bn4b  = (const float*)d_in[5];
    const float* posw  = (const float*)d_in[6];
    const float* posb  = (const float*)d_in[7];
    const float* w1    = (const float*)d_in[8];
    // d_in[9] = dec_b1: constant column shift removed exactly by BatchNorm -> unused
    const float* g1    = (const float*)d_in[10];
    const float* b1    = (const float*)d_in[11];
    const float* w2    = (const float*)d_in[12];
    const float* b2    = (const float*)d_in[13];
    float* out = (float*)d_out;

    char* ws = (char*)d_ws;
    const size_t OFF_STATS1 = 4096;
    const size_t OFF_AE = 16384;
    const size_t OFF_BT = OFF_AE + (size_t)N_ROWS * KE * 2;     // 46,153,728
    const size_t OFF_H  = OFF_BT + (size_t)HID * KPAD * 2;      // 51,068,928
    const size_t NEED   = OFF_H + (size_t)N_ROWS * HID * 2;     // 185,286,656
    if (ws_size < NEED) return;

    float* stats4 = (float*)(ws);
    float* stats1 = (float*)(ws + OFF_STATS1);
    unsigned short* Ae = (unsigned short*)(ws + OFF_AE);
    unsigned short* Bt = (unsigned short*)(ws + OFF_BT);
    unsigned short* H  = (unsigned short*)(ws + OFF_H);

    hipMemsetAsync(ws, 0, 16384, stream);
    bn4_stats_k<<<256, 256, 0, stream>>>(boxes, stats4);
    build_ae_k<<<1024, 256, 0, stream>>>(dist, boxes, objw, bn4g, bn4b, posw, posb, stats4, Ae);
    transpose_w1_k<<<2400, 256, 0, stream>>>(w1, Bt);
    gemm1_k<<<4096, 256, 0, stream>>>(feat, Ae, Bt, H);
    bn1_stats_k<<<1024, 256, 0, stream>>>(H, stats1);
    final_k<<<512, 256, 0, stream>>>(H, stats1, g1, b1, w2, b2, out);
}

// Round 2
// 1400.051 us; speedup vs baseline: 1.2896x; 1.2896x over previous
//
#include <hip/hip_runtime.h>

#define N_ROWS 65536
#define KF 2048
#define KE 352
#define KPAD 2400
#define HID 1024
#define NCLS 37
#define NPAD 48

// ---------- helpers ----------
__device__ __forceinline__ unsigned short f2bf(float x) {  // RNE
    unsigned u = __float_as_uint(x);
    return (unsigned short)((u + 0x7FFFu + ((u >> 16) & 1u)) >> 16);
}
__device__ __forceinline__ float bf2f(unsigned short h) {
    return __uint_as_float(((unsigned)h) << 16);
}
__device__ __forceinline__ unsigned pack_rne(float a, float b) {
    return (unsigned)f2bf(a) | ((unsigned)f2bf(b) << 16);
}
// truncation pack (1 v_perm_b32); batchnorm cancels the uniform scale bias
__device__ __forceinline__ unsigned pack_trunc(float a, float b) {
    return __byte_perm(__float_as_uint(a), __float_as_uint(b), 0x7632);
}

typedef __bf16 bf16x8 __attribute__((ext_vector_type(8)));
typedef float f32x4 __attribute__((ext_vector_type(4)));

__device__ __forceinline__ void gl2lds16(const void* g, void* l) {
    __builtin_amdgcn_global_load_lds((const __attribute__((address_space(1))) void*)g,
                                     (__attribute__((address_space(3))) void*)l, 16, 0, 0);
}

// ---------- K0: bn4 stats over center_size(boxes[:,1:5]) ----------
__global__ __launch_bounds__(256) void bn4_stats_k(const float* __restrict__ boxes,
                                                   float* __restrict__ stats4) {
    const int tid = threadIdx.x;
    const int r = blockIdx.x * 256 + tid;
    const float* b = boxes + (size_t)r * 5;
    float x1 = b[1], y1 = b[2], x2 = b[3], y2 = b[4];
    float w = x2 - x1, h = y2 - y1;
    float cx = x1 + 0.5f * w, cy = y1 + 0.5f * h;
    float v[8] = {cx, cy, w, h, cx * cx, cy * cy, w * w, h * h};
    #pragma unroll
    for (int c = 0; c < 8; c++) {
        #pragma unroll
        for (int o = 32; o > 0; o >>= 1) v[c] += __shfl_down(v[c], o, 64);
    }
    __shared__ float sh[4][8];
    const int lane = tid & 63, wv = tid >> 6;
    if (lane == 0) {
        #pragma unroll
        for (int c = 0; c < 8; c++) sh[wv][c] = v[c];
    }
    __syncthreads();
    if (tid < 8) atomicAdd(&stats4[tid], sh[0][tid] + sh[1][tid] + sh[2][tid] + sh[3][tid]);
}

// ---------- K1: build E = [obj_embed(200) | pos(128) | 0(24)] bf16 ----------
__global__ __launch_bounds__(256) void build_ae_k(
    const float* __restrict__ dist, const float* __restrict__ boxes,
    const float* __restrict__ objw, const float* __restrict__ bn4g,
    const float* __restrict__ bn4b, const float* __restrict__ posw,
    const float* __restrict__ posb, const float* __restrict__ stats4,
    unsigned short* __restrict__ Ae) {
    __shared__ __align__(16) float Wsh[7200];   // obj_embed_w [36,200]
    __shared__ __align__(16) float Psh[640];    // pos_w [4,128] + pos_b [128]
    __shared__ float Csh[64 * 4];
    __shared__ float sc4[4], sf4[4];
    const int t = threadIdx.x;
    const int r0 = blockIdx.x * 64;
    for (int i = t; i < 7200; i += 256) Wsh[i] = objw[i];
    for (int i = t; i < 512; i += 256) Psh[i] = posw[i];
    if (t < 128) Psh[512 + t] = posb[t];
    if (t < 4) {
        float m = stats4[t] * (1.0f / 65536.0f);
        float var = stats4[4 + t] * (1.0f / 65536.0f) - m * m;
        float sc = bn4g[t] * rsqrtf(var + 1e-5f);
        sc4[t] = sc; sf4[t] = bn4b[t] - m * sc;
    }
    __syncthreads();
    if (t < 64) {
        const float* b = boxes + (size_t)(r0 + t) * 5;
        float x1 = b[1], y1 = b[2], x2 = b[3], y2 = b[4];
        float w = x2 - x1, h = y2 - y1;
        float cx = x1 + 0.5f * w, cy = y1 + 0.5f * h;
        Csh[t * 4 + 0] = cx * sc4[0] + sf4[0];
        Csh[t * 4 + 1] = cy * sc4[1] + sf4[1];
        Csh[t * 4 + 2] = w * sc4[2] + sf4[2];
        Csh[t * 4 + 3] = h * sc4[3] + sf4[3];
    }
    __syncthreads();
    const int r = t >> 2, q = t & 3;
    float d[36];
    #pragma unroll
    for (int ii = 0; ii < 9; ii++)
        *(float4*)&d[ii * 4] = *(const float4*)(dist + (size_t)(r0 + r) * 36 + ii * 4);
    unsigned short* arow = Ae + (size_t)(r0 + r) * KE;
    for (int gg = q; gg < 50; gg += 4) {
        int c = gg * 4;
        float4 s = {0.f, 0.f, 0.f, 0.f};
        #pragma unroll
        for (int i = 0; i < 36; i++) {
            float4 wv = *(const float4*)&Wsh[i * 200 + c];
            s.x = fmaf(d[i], wv.x, s.x); s.y = fmaf(d[i], wv.y, s.y);
            s.z = fmaf(d[i], wv.z, s.z); s.w = fmaf(d[i], wv.w, s.w);
        }
        uint2 p; p.x = pack_rne(s.x, s.y); p.y = pack_rne(s.z, s.w);
        *(uint2*)(arow + c) = p;
    }
    const float c0v = Csh[r * 4 + 0], c1v = Csh[r * 4 + 1];
    const float c2v = Csh[r * 4 + 2], c3v = Csh[r * 4 + 3];
    for (int gg = q; gg < 32; gg += 4) {
        int c = gg * 4;
        float4 s = *(const float4*)&Psh[512 + c];
        float4 w0 = *(const float4*)&Psh[0 * 128 + c];
        float4 w1 = *(const float4*)&Psh[1 * 128 + c];
        float4 w2v = *(const float4*)&Psh[2 * 128 + c];
        float4 w3 = *(const float4*)&Psh[3 * 128 + c];
        s.x = fmaf(c0v, w0.x, fmaf(c1v, w1.x, fmaf(c2v, w2v.x, fmaf(c3v, w3.x, s.x))));
        s.y = fmaf(c0v, w0.y, fmaf(c1v, w1.y, fmaf(c2v, w2v.y, fmaf(c3v, w3.y, s.y))));
        s.z = fmaf(c0v, w0.z, fmaf(c1v, w1.z, fmaf(c2v, w2v.z, fmaf(c3v, w3.z, s.z))));
        s.w = fmaf(c0v, w0.w, fmaf(c1v, w1.w, fmaf(c2v, w2v.w, fmaf(c3v, w3.w, s.w))));
        s.x = fmaxf(s.x, 0.f); s.y = fmaxf(s.y, 0.f);
        s.z = fmaxf(s.z, 0.f); s.w = fmaxf(s.w, 0.f);
        uint2 p; p.x = pack_rne(s.x, s.y); p.y = pack_rne(s.z, s.w);
        *(uint2*)(arow + 200 + c) = p;
    }
    for (int f = t; f < 384; f += 256) {
        int rr = f / 6, gg = f % 6;
        uint2 z; z.x = 0u; z.y = 0u;
        *(uint2*)(Ae + (size_t)(r0 + rr) * KE + 328 + gg * 4) = z;
    }
}

// ---------- K2: Bt[n][k] = dec_w1[k][n] (bf16, zero-padded K) ----------
__global__ __launch_bounds__(256) void transpose_w1_k(const float* __restrict__ w1,
                                                      unsigned short* __restrict__ Bt) {
    __shared__ float sh[32][33];
    const int bk = (blockIdx.x % 75) * 32;
    const int bn = (blockIdx.x / 75) * 32;
    const int tx = threadIdx.x & 31, ty = threadIdx.x >> 5;
    for (int yy = ty; yy < 32; yy += 8) {
        int k = bk + yy;
        sh[tx][yy] = (k < 2376) ? w1[(size_t)k * HID + bn + tx] : 0.0f;
    }
    __syncthreads();
    for (int row = ty; row < 32; row += 8)
        Bt[(size_t)(bn + row) * KPAD + bk + tx] = f2bf(sh[row][tx]);
}

// ---------- K2b: w2t[n][k] = bf16(dec_w2[k][n]), n padded to 48 ----------
__global__ __launch_bounds__(256) void w2t_pack_k(const float* __restrict__ w2,
                                                  unsigned short* __restrict__ w2t) {
    const int n = blockIdx.x;           // 48
    for (int k = threadIdx.x; k < HID; k += 256)
        w2t[(size_t)n * HID + k] = (n < NCLS) ? f2bf(w2[(size_t)k * NCLS + n]) : (unsigned short)0;
}

// ---------- K3: main GEMM  H[65536,1024] = bf16([F|E]) @ bf16(W1) ----------
#define COMPUTE_STEP()                                                                   \
    do {                                                                                 \
        bf16x8 af[4], bfr[4];                                                            \
        _Pragma("unroll") for (int i = 0; i < 4; i++)                                    \
            af[i] = *(const bf16x8*)(a_sh + (mw + i * 16 + fm) * 32 + fq * 8);           \
        _Pragma("unroll") for (int j = 0; j < 4; j++)                                    \
            bfr[j] = *(const bf16x8*)(b_sh + (nw + j * 16 + fm) * 32 + fq * 8);          \
        _Pragma("unroll") for (int i = 0; i < 4; i++)                                    \
            _Pragma("unroll") for (int j = 0; j < 4; j++)                                \
                acc[i][j] = __builtin_amdgcn_mfma_f32_16x16x32_bf16(af[i], bfr[j],       \
                                                                    acc[i][j], 0, 0, 0); \
    } while (0)

__global__ __launch_bounds__(256) void gemm1_k(
    const float* __restrict__ F, const unsigned short* __restrict__ Ae,
    const unsigned short* __restrict__ Bt, unsigned short* __restrict__ H) {
    __shared__ __align__(16) unsigned short a_sh[128 * 32];
    __shared__ __align__(16) unsigned short b_sh[128 * 32];
    const int tid = threadIdx.x;
    const int lane = tid & 63;
    const int wv = tid >> 6;
    // XCD-aware swizzle: blockIdx % 8 = XCD. For a fixed XCD x, consecutive
    // t walk n fastest with m fixed for 8 in a row -> the 8 blocks sharing an
    // A row-tile are co-XCD and temporally adjacent -> A re-reads hit that
    // XCD's 4 MB L2 instead of HBM (round-1 FETCH was 4.3x the F array).
    const int x = blockIdx.x & 7;
    const int t8 = blockIdx.x >> 3;          // [0, 512)
    const int n0 = (t8 & 7) * 128;
    const int m0 = (((t8 >> 3) << 3) | x) * 128;
    const int mw = (wv & 1) * 64, nw = (wv >> 1) * 64;
    const int fm = lane & 15, fq = lane >> 4;

    f32x4 acc[4][4];
    const f32x4 zero = {0.f, 0.f, 0.f, 0.f};
    #pragma unroll
    for (int i = 0; i < 4; i++)
        #pragma unroll
        for (int j = 0; j < 4; j++) acc[i][j] = zero;

    const float* fbase = F + (size_t)(m0 + (tid >> 3)) * KF + (tid & 7) * 4;
    const unsigned short* btbase = Bt + (size_t)(n0 + (tid >> 2)) * KPAD + (tid & 3) * 8;
    const unsigned short* aebase = Ae + (size_t)(m0 + (tid >> 2)) * KE + (tid & 3) * 8;
    unsigned short* a_dst32 = a_sh + (tid >> 3) * 32 + (tid & 7) * 4;
    unsigned short* a_dst = a_sh + tid * 8;
    unsigned short* b_dst = b_sh + tid * 8;

    // register prefetch of first fp32 A tile
    float4 av0 = *(const float4*)(fbase + 0);
    float4 av1 = *(const float4*)(fbase + 32 * KF);
    float4 av2 = *(const float4*)(fbase + 64 * KF);
    float4 av3 = *(const float4*)(fbase + 96 * KF);

    for (int k0 = 0; k0 < KF; k0 += 32) {
        __syncthreads();                       // prev compute done
        uint2 p0; p0.x = pack_trunc(av0.x, av0.y); p0.y = pack_trunc(av0.z, av0.w);
        uint2 p1; p1.x = pack_trunc(av1.x, av1.y); p1.y = pack_trunc(av1.z, av1.w);
        uint2 p2; p2.x = pack_trunc(av2.x, av2.y); p2.y = pack_trunc(av2.z, av2.w);
        uint2 p3; p3.x = pack_trunc(av3.x, av3.y); p3.y = pack_trunc(av3.z, av3.w);
        *(uint2*)(a_dst32 + 0)    = p0;
        *(uint2*)(a_dst32 + 1024) = p1;
        *(uint2*)(a_dst32 + 2048) = p2;
        *(uint2*)(a_dst32 + 3072) = p3;
        gl2lds16(btbase + k0, b_dst);
        gl2lds16(btbase + k0 + 64 * KPAD, b_dst + 2048);
        __syncthreads();                       // staging visible
        if (k0 + 32 < KF) {                    // prefetch next tile; latency hides under MFMA
            av0 = *(const float4*)(fbase + k0 + 32);
            av1 = *(const float4*)(fbase + k0 + 32 + 32 * KF);
            av2 = *(const float4*)(fbase + k0 + 32 + 64 * KF);
            av3 = *(const float4*)(fbase + k0 + 32 + 96 * KF);
        }
        COMPUTE_STEP();
    }
    for (int k0 = KF; k0 < KPAD; k0 += 32) {   // obj_embed/pos columns (bf16, async)
        __syncthreads();
        gl2lds16(aebase + (k0 - KF), a_dst);
        gl2lds16(aebase + (k0 - KF) + 64 * KE, a_dst + 2048);
        gl2lds16(btbase + k0, b_dst);
        gl2lds16(btbase + k0 + 64 * KPAD, b_dst + 2048);
        __syncthreads();
        COMPUTE_STEP();
    }
    #pragma unroll
    for (int i = 0; i < 4; i++)
        #pragma unroll
        for (int j = 0; j < 4; j++)
            #pragma unroll
            for (int r = 0; r < 4; r++) {
                int row = m0 + mw + i * 16 + fq * 4 + r;
                int col = n0 + nw + j * 16 + fm;
                H[(size_t)row * HID + col] = f2bf(acc[i][j][r]);
            }
}

// ---------- K4: bn1 column stats over H ----------
__global__ __launch_bounds__(256) void bn1_stats_k(const unsigned short* __restrict__ H,
                                                   float* __restrict__ stats1) {
    const int t = threadIdx.x;
    const int cb = blockIdx.x & 3;     // 4 col-blocks of 256
    const int rc = blockIdx.x >> 2;    // 256 row-chunks of 256
    const int c0 = cb * 256 + (t & 31) * 8;
    const int r0 = rc * 256 + (t >> 5);
    float s[8] = {0, 0, 0, 0, 0, 0, 0, 0}, q[8] = {0, 0, 0, 0, 0, 0, 0, 0};
    for (int i = 0; i < 32; i++) {
        const unsigned short* p = H + (size_t)(r0 + i * 8) * HID + c0;
        uint4 raw = *(const uint4*)p;
        unsigned wds[4] = {raw.x, raw.y, raw.z, raw.w};
        #pragma unroll
        for (int j = 0; j < 4; j++) {
            float v0 = bf2f((unsigned short)(wds[j] & 0xFFFFu));
            float v1 = bf2f((unsigned short)(wds[j] >> 16));
            s[2 * j] += v0; q[2 * j] += v0 * v0;
            s[2 * j + 1] += v1; q[2 * j + 1] += v1 * v1;
        }
    }
    __shared__ float sh[2048];
    #pragma unroll
    for (int j = 0; j < 8; j++) sh[t * 8 + j] = s[j];
    __syncthreads();
    if (t < 32) {
        float tot[8] = {0, 0, 0, 0, 0, 0, 0, 0};
        for (int rl = 0; rl < 8; rl++)
            #pragma unroll
            for (int j = 0; j < 8; j++) tot[j] += sh[(rl * 32 + t) * 8 + j];
        #pragma unroll
        for (int j = 0; j < 8; j++) atomicAdd(&stats1[cb * 256 + t * 8 + j], tot[j]);
    }
    __syncthreads();
    #pragma unroll
    for (int j = 0; j < 8; j++) sh[t * 8 + j] = q[j];
    __syncthreads();
    if (t < 32) {
        float tot[8] = {0, 0, 0, 0, 0, 0, 0, 0};
        for (int rl = 0; rl < 8; rl++)
            #pragma unroll
            for (int j = 0; j < 8; j++) tot[j] += sh[(rl * 32 + t) * 8 + j];
        #pragma unroll
        for (int j = 0; j < 8; j++) atomicAdd(&stats1[HID + cb * 256 + t * 8 + j], tot[j]);
    }
}

// ---------- K5: out = relu(bn1(H)) @ w2 + b2  via bf16 MFMA (N padded to 48) ----------
__global__ __launch_bounds__(256) void final_k(
    const unsigned short* __restrict__ H, const float* __restrict__ stats1,
    const float* __restrict__ g1, const float* __restrict__ b1,
    const unsigned short* __restrict__ w2t, const float* __restrict__ b2,
    float* __restrict__ out) {
    __shared__ __align__(16) float scs[HID], sfs[HID];
    __shared__ __align__(16) unsigned short psh[128 * 32];  // P tile (bn+relu, bf16)
    __shared__ __align__(16) unsigned short wsh[NPAD * 32]; // w2t chunk
    const int t = threadIdx.x;
    const int r0 = blockIdx.x * 128;
    const int lane = t & 63, wv = t >> 6;
    const int fm = lane & 15, fq = lane >> 4;
    const int mw = wv * 32;

    for (int k = t; k < HID; k += 256) {
        float m = stats1[k] * (1.0f / 65536.0f);
        float var = stats1[HID + k] * (1.0f / 65536.0f) - m * m;
        float sc = g1[k] * rsqrtf(var + 1e-5f);
        scs[k] = sc; sfs[k] = b1[k] - m * sc;
    }
    f32x4 acc[2][3];
    const f32x4 zero = {0.f, 0.f, 0.f, 0.f};
    #pragma unroll
    for (int i = 0; i < 2; i++)
        #pragma unroll
        for (int j = 0; j < 3; j++) acc[i][j] = zero;
    __syncthreads();

    const int prow = t >> 2, pq = t & 3;
    for (int k0 = 0; k0 < HID; k0 += 32) {
        __syncthreads();   // protect psh/wsh from previous iteration's readers
        const int kb = k0 + pq * 8;
        const float4 sc0 = *(const float4*)&scs[kb];
        const float4 sc1 = *(const float4*)&scs[kb + 4];
        const float4 sf0 = *(const float4*)&sfs[kb];
        const float4 sf1 = *(const float4*)&sfs[kb + 4];
        const float scv[8] = {sc0.x, sc0.y, sc0.z, sc0.w, sc1.x, sc1.y, sc1.z, sc1.w};
        const float sfv[8] = {sf0.x, sf0.y, sf0.z, sf0.w, sf1.x, sf1.y, sf1.z, sf1.w};
        #pragma unroll
        for (int p = 0; p < 2; p++) {
            const int rr = prow + p * 64;
            uint4 raw = *(const uint4*)(H + (size_t)(r0 + rr) * HID + kb);
            unsigned wds[4] = {raw.x, raw.y, raw.z, raw.w};
            uint4 o;
            unsigned ow[4];
            #pragma unroll
            for (int j = 0; j < 4; j++) {
                float v0 = bf2f((unsigned short)(wds[j] & 0xFFFFu));
                float v1 = bf2f((unsigned short)(wds[j] >> 16));
                v0 = fmaxf(fmaf(v0, scv[2 * j], sfv[2 * j]), 0.0f);
                v1 = fmaxf(fmaf(v1, scv[2 * j + 1], sfv[2 * j + 1]), 0.0f);
                ow[j] = pack_rne(v0, v1);
            }
            o.x = ow[0]; o.y = ow[1]; o.z = ow[2]; o.w = ow[3];
            *(uint4*)&psh[rr * 32 + pq * 8] = o;
        }
        if (t < 4 * NPAD) {
            const int n = t >> 2;
            uint4 w = *(const uint4*)(w2t + (size_t)n * HID + kb);
            *(uint4*)&wsh[n * 32 + pq * 8] = w;
        }
        __syncthreads();
        bf16x8 af[2], bfr[3];
        #pragma unroll
        for (int i = 0; i < 2; i++)
            af[i] = *(const bf16x8*)(psh + (mw + i * 16 + fm) * 32 + fq * 8);
        #pragma unroll
        for (int j = 0; j < 3; j++)
            bfr[j] = *(const bf16x8*)(wsh + (j * 16 + fm) * 32 + fq * 8);
        #pragma unroll
        for (int i = 0; i < 2; i++)
            #pragma unroll
            for (int j = 0; j < 3; j++)
                acc[i][j] = __builtin_amdgcn_mfma_f32_16x16x32_bf16(af[i], bfr[j], acc[i][j], 0, 0, 0);
    }
    #pragma unroll
    for (int i = 0; i < 2; i++)
        #pragma unroll
        for (int j = 0; j < 3; j++) {
            const int col = j * 16 + fm;
            if (col < NCLS) {
                const float bb = b2[col];
                #pragma unroll
                for (int r = 0; r < 4; r++) {
                    const int row = r0 + mw + i * 16 + fq * 4 + r;
                    out[(size_t)row * NCLS + col] = acc[i][j][r] + bb;
                }
            }
        }
}

// ---------- launch ----------
extern "C" void kernel_launch(void* const* d_in, const int* in_sizes, int n_in,
                              void* d_out, int out_size, void* d_ws, size_t ws_size,
                              hipStream_t stream) {
    (void)in_sizes; (void)n_in; (void)out_size;
    const float* dist  = (const float*)d_in[0];
    const float* boxes = (const float*)d_in[1];
    const float* feat  = (const float*)d_in[2];
    const float* objw  = (const float*)d_in[3];
    const float* bn4g  = (const float*)d_in[4];
    const float* bn4b  = (const float*)d_in[5];
    const float* posw  = (const float*)d_in[6];
    const float* posb  = (const float*)d_in[7];
    const float* w1    = (const float*)d_in[8];
    // d_in[9] = dec_b1: constant column shift removed exactly by BatchNorm -> unused
    const float* g1    = (const float*)d_in[10];
    const float* b1    = (const float*)d_in[11];
    const float* w2    = (const float*)d_in[12];
    const float* b2    = (const float*)d_in[13];
    float* out = (float*)d_out;

    char* ws = (char*)d_ws;
    const size_t OFF_STATS1 = 4096;
    const size_t OFF_W2T = 16384;
    const size_t OFF_AE = 131072;
    const size_t OFF_BT = OFF_AE + (size_t)N_ROWS * KE * 2;     // +46,137,344
    const size_t OFF_H  = OFF_BT + (size_t)HID * KPAD * 2;      // +4,915,200
    const size_t NEED   = OFF_H + (size_t)N_ROWS * HID * 2;     // ~185.4 MB
    if (ws_size < NEED) return;

    float* stats4 = (float*)(ws);
    float* stats1 = (float*)(ws + OFF_STATS1);
    unsigned short* w2t = (unsigned short*)(ws + OFF_W2T);
    unsigned short* Ae = (unsigned short*)(ws + OFF_AE);
    unsigned short* Bt = (unsigned short*)(ws + OFF_BT);
    unsigned short* H  = (unsigned short*)(ws + OFF_H);

    hipMemsetAsync(ws, 0, 16384, stream);
    bn4_stats_k<<<256, 256, 0, stream>>>(boxes, stats4);
    build_ae_k<<<1024, 256, 0, stream>>>(dist, boxes, objw, bn4g, bn4b, posw, posb, stats4, Ae);
    transpose_w1_k<<<2400, 256, 0, stream>>>(w1, Bt);
    w2t_pack_k<<<NPAD, 256, 0, stream>>>(w2, w2t);
    gemm1_k<<<4096, 256, 0, stream>>>(feat, Ae, Bt, H);
    bn1_stats_k<<<1024, 256, 0, stream>>>(H, stats1);
    final_k<<<512, 256, 0, stream>>>(H, stats1, g1, b1, w2t, b2, out);
}